// Round 11
// baseline (161.885 us; speedup 1.0000x reference)
//
#include <hip/hip_runtime.h>

typedef unsigned short ushort_t;
typedef __bf16 bf16x8 __attribute__((ext_vector_type(8)));
typedef float f32x4 __attribute__((ext_vector_type(4)));

__device__ __forceinline__ ushort_t f2bf(float f) {
    unsigned u = __builtin_bit_cast(unsigned, f);
    unsigned r = (u + 0x7fffu + ((u >> 16) & 1u)) >> 16;
    return (ushort_t)r;
}
__device__ __forceinline__ float bf2f(ushort_t u) {
    return __builtin_bit_cast(float, (unsigned)u << 16);
}

__device__ __forceinline__ void async16(const ushort_t* g, void* lds) {
    __builtin_amdgcn_global_load_lds(
        (const __attribute__((address_space(1))) void*)g,
        (__attribute__((address_space(3))) void*)lds, 16, 0, 0);
}

// ---------------- merged prep: zero xsum + bf16-convert all weights + helperT ----------------

__global__ __launch_bounds__(256)
void k_prep(const float* __restrict__ wu, const float* __restrict__ wv,
            const float* __restrict__ cpw, const float* __restrict__ hw,
            ushort_t* __restrict__ wu_bf, ushort_t* __restrict__ wv_bf,
            ushort_t* __restrict__ cproj, ushort_t* __restrict__ hT,
            float* __restrict__ xsum)
{
    const int gid = blockIdx.x * 256 + threadIdx.x;
    if (gid < 8192) xsum[gid] = 0.0f;
    const int st = gridDim.x * 256;
    for (int i = gid; i < 1048576; i += st) {
        wu_bf[i] = f2bf(wu[i]);
        wv_bf[i] = f2bf(wv[i]);
        cproj[i] = f2bf(cpw[i]);
        if (i < 65536) {
            int c = i >> 6, d = i & 63;
            hT[i] = f2bf(hw[d * 1024 + c]);   // helperT[c][d] = helper_w[d][c]
        }
    }
}

// ---------------- transpose + convert: x fp32 -> x_bf, xT_bf, xsum ----------------

__global__ __launch_bounds__(256)
void k_trans(const float* __restrict__ x, ushort_t* __restrict__ xbf,
             ushort_t* __restrict__ xT, float* __restrict__ xsum)
{
    __shared__ ushort_t T[256 * 130];
    __shared__ float xs[128];
    const int t0 = blockIdx.x * 256, c0 = blockIdx.y * 128, b = blockIdx.z;
    const int tid = threadIdx.x;
    const int w = tid >> 6, lane = tid & 63;
    const int lh = lane >> 5;
    const int k32 = lane & 31;

    if (tid < 128) xs[tid] = 0.0f;
    __syncthreads();

    float ps[4] = {0.f, 0.f, 0.f, 0.f};
    #pragma unroll 4
    for (int it = 0; it < 32; ++it) {
        const int r = it * 8 + w * 2 + lh;
        const long gi = ((long)(b * 2048 + t0 + r)) * 1024 + c0 + k32 * 4;
        float4 f = *(const float4*)&x[gi];
        ushort4 o;
        o.x = f2bf(f.x); o.y = f2bf(f.y); o.z = f2bf(f.z); o.w = f2bf(f.w);
        *(ushort4*)&xbf[gi] = o;
        *(ushort4*)&T[r * 130 + k32 * 4] = o;
        ps[0] += bf2f(o.x); ps[1] += bf2f(o.y); ps[2] += bf2f(o.z); ps[3] += bf2f(o.w);
    }
    #pragma unroll
    for (int k = 0; k < 4; ++k) ps[k] += __shfl_xor(ps[k], 32, 64);
    if (lh == 0) {
        #pragma unroll
        for (int k = 0; k < 4; ++k) atomicAdd(&xs[k32 * 4 + k], ps[k]);
    }
    __syncthreads();

    for (int i = 0; i < 32; ++i) {
        const int c = w * 32 + i;
        ushort_t* dst = &xT[((long)(b * 1024 + c0 + c)) * 2048 + t0];
        #pragma unroll
        for (int j = 0; j < 2; ++j) {
            const int t = 2 * lane + 128 * j;
            unsigned lo = T[t * 130 + c];
            unsigned hi = T[(t + 1) * 130 + c];
            *(unsigned*)(dst + 128 * j + 2 * lane) = lo | (hi << 16);
        }
    }
    if (tid < 128) atomicAdd(&xsum[b * 1024 + c0 + tid], xs[tid]);
}

// ---------------- SYRK: XtX[b] = xT[b] @ xT[b]^T, 128x64 upper tiles + mirror, XCD-affine ----------------

__global__ __launch_bounds__(256)
void k_syrk(const ushort_t* __restrict__ xT, ushort_t* __restrict__ XtX)
{
    __shared__ ushort_t smem[24576];
    const int id = blockIdx.x;
    const int z = id & 7;
    int L = id >> 3, bi = 0;
    while (L >= 16 - 2 * bi) { L -= 16 - 2 * bi; ++bi; }
    const int cj = 2 * bi + L;
    const ushort_t* base = xT + (long)z * 2097152;
    const ushort_t* Ab = base + (long)bi * 128 * 2048;
    const ushort_t* Bb = base + (long)cj * 64 * 2048;
    ushort_t* C = XtX + (long)z * 1048576;
    const int tid = threadIdx.x;
    const int w = tid >> 6;
    const int lane = tid & 63;
    const int l15 = lane & 15, l4 = lane >> 4;
    const int wr = (w >> 1) * 64, wc = (w & 1) * 32;

    f32x4 acc[4][2] = {};
    const int srow = lane >> 3;
    const int gchunk = (lane & 7) ^ srow;

    #pragma unroll
    for (int q = 0; q < 4; ++q) {
        const int seg = w * 4 + q;
        async16(Ab + (long)(seg * 8 + srow) * 2048 + gchunk * 8, (char*)smem + seg * 1024);
    }
    #pragma unroll
    for (int q = 0; q < 2; ++q) {
        const int seg = w * 2 + q;
        async16(Bb + (long)(seg * 8 + srow) * 2048 + gchunk * 8, (char*)smem + 32768 + seg * 1024);
    }
    __syncthreads();

    int cur = 0;
    for (int kt = 0; kt < 2048; kt += 64) {
        if (kt + 64 < 2048) {
            const int nb = cur ^ 1;
            #pragma unroll
            for (int q = 0; q < 4; ++q) {
                const int seg = w * 4 + q;
                async16(Ab + (long)(seg * 8 + srow) * 2048 + kt + 64 + gchunk * 8,
                        (char*)smem + nb * 16384 + seg * 1024);
            }
            #pragma unroll
            for (int q = 0; q < 2; ++q) {
                const int seg = w * 2 + q;
                async16(Bb + (long)(seg * 8 + srow) * 2048 + kt + 64 + gchunk * 8,
                        (char*)smem + 32768 + nb * 8192 + seg * 1024);
            }
        }
        const ushort_t* Acur = smem + cur * 8192;
        const ushort_t* Bcur = smem + 16384 + cur * 4096;
        #pragma unroll
        for (int kk = 0; kk < 2; ++kk) {
            bf16x8 af[4], bfr[2];
            const int swz = ((kk * 4 + l4) ^ (l15 & 7)) * 8;
            #pragma unroll
            for (int i = 0; i < 4; ++i)
                af[i] = *(const bf16x8*)&Acur[(wr + i * 16 + l15) * 64 + swz];
            #pragma unroll
            for (int nf = 0; nf < 2; ++nf)
                bfr[nf] = *(const bf16x8*)&Bcur[(wc + nf * 16 + l15) * 64 + swz];
            __builtin_amdgcn_s_setprio(1);
            #pragma unroll
            for (int i = 0; i < 4; ++i)
                #pragma unroll
                for (int nf = 0; nf < 2; ++nf)
                    acc[i][nf] = __builtin_amdgcn_mfma_f32_16x16x32_bf16(af[i], bfr[nf], acc[i][nf], 0, 0, 0);
            __builtin_amdgcn_s_setprio(0);
        }
        __syncthreads();
        cur ^= 1;
    }

    #pragma unroll
    for (int i = 0; i < 4; ++i) {
        #pragma unroll
        for (int nf = 0; nf < 2; ++nf) {
            const int row0 = bi * 128 + wr + i * 16 + l4 * 4;
            const int col  = cj * 64 + wc + nf * 16 + l15;
            #pragma unroll
            for (int e = 0; e < 4; ++e)
                C[(long)(row0 + e) * 1024 + col] = f2bf(acc[i][nf][e]);
        }
    }
    __syncthreads();
    #pragma unroll
    for (int i = 0; i < 4; ++i)
        #pragma unroll
        for (int nf = 0; nf < 2; ++nf)
            #pragma unroll
            for (int e = 0; e < 4; ++e)
                smem[(wr + i * 16 + l4 * 4 + e) * 66 + wc + nf * 16 + l15] = f2bf(acc[i][nf][e]);
    __syncthreads();
    const int nr = tid & 63;
    const int mh = tid >> 6;
    unsigned wds[16];
    #pragma unroll
    for (int u = 0; u < 16; ++u) {
        const int m = mh * 32 + u * 2;
        unsigned lo = smem[m * 66 + nr];
        unsigned hi = smem[(m + 1) * 66 + nr];
        wds[u] = lo | (hi << 16);
    }
    #pragma unroll
    for (int v = 0; v < 4; ++v) {
        uint4 pk; unsigned* pw = (unsigned*)&pk;
        pw[0] = wds[v * 4]; pw[1] = wds[v * 4 + 1]; pw[2] = wds[v * 4 + 2]; pw[3] = wds[v * 4 + 3];
        *(uint4*)&C[(long)(cj * 64 + nr) * 1024 + bi * 128 + mh * 32 + v * 8] = pk;
    }
}

// ---------------- W2 = wu @ XtX[b] : 256x128 tile, BK=64, dbuf, 96 KB LDS ----------------

__global__ __launch_bounds__(256)
void k_w2(const ushort_t* __restrict__ wu, const ushort_t* __restrict__ XtX,
          ushort_t* __restrict__ W2)
{
    __shared__ ushort_t smem[49152];
    const int id = blockIdx.x;
    const int z = id & 7;
    const int t = id >> 3;
    const int bx = t & 3, by = t >> 2;
    const int m0 = bx * 256, n0 = by * 128;
    const ushort_t* Ab = wu + (long)m0 * 1024;
    const ushort_t* Bb = XtX + (long)z * 1048576 + (long)n0 * 1024;
    ushort_t* C = W2 + (long)z * 1048576;
    const int tid = threadIdx.x;
    const int w = tid >> 6;
    const int lane = tid & 63;
    const int l15 = lane & 15, l4 = lane >> 4;
    const int wr = (w >> 1) * 128, wc = (w & 1) * 64;

    f32x4 acc[8][4] = {};
    const int srow = lane >> 3;
    const int gchunk = (lane & 7) ^ srow;

    #pragma unroll
    for (int q = 0; q < 8; ++q) {
        const int seg = w * 8 + q;
        async16(Ab + (long)(seg * 8 + srow) * 1024 + gchunk * 8, (char*)smem + seg * 1024);
    }
    #pragma unroll
    for (int q = 0; q < 4; ++q) {
        const int seg = w * 4 + q;
        async16(Bb + (long)(seg * 8 + srow) * 1024 + gchunk * 8, (char*)smem + 65536 + seg * 1024);
    }
    __syncthreads();

    int cur = 0;
    for (int kt = 0; kt < 1024; kt += 64) {
        if (kt + 64 < 1024) {
            const int nb = cur ^ 1;
            #pragma unroll
            for (int q = 0; q < 8; ++q) {
                const int seg = w * 8 + q;
                async16(Ab + (long)(seg * 8 + srow) * 1024 + kt + 64 + gchunk * 8,
                        (char*)smem + nb * 32768 + seg * 1024);
            }
            #pragma unroll
            for (int q = 0; q < 4; ++q) {
                const int seg = w * 4 + q;
                async16(Bb + (long)(seg * 8 + srow) * 1024 + kt + 64 + gchunk * 8,
                        (char*)smem + 65536 + nb * 16384 + seg * 1024);
            }
        }
        const ushort_t* Acur = smem + cur * 16384;
        const ushort_t* Bcur = smem + 32768 + cur * 8192;
        #pragma unroll
        for (int kk = 0; kk < 2; ++kk) {
            bf16x8 af[8], bfr[4];
            const int swz = ((kk * 4 + l4) ^ (l15 & 7)) * 8;
            #pragma unroll
            for (int i = 0; i < 8; ++i)
                af[i] = *(const bf16x8*)&Acur[(wr + i * 16 + l15) * 64 + swz];
            #pragma unroll
            for (int j = 0; j < 4; ++j)
                bfr[j] = *(const bf16x8*)&Bcur[(wc + j * 16 + l15) * 64 + swz];
            __builtin_amdgcn_s_setprio(1);
            #pragma unroll
            for (int i = 0; i < 8; ++i)
                #pragma unroll
                for (int j = 0; j < 4; ++j)
                    acc[i][j] = __builtin_amdgcn_mfma_f32_16x16x32_bf16(af[i], bfr[j], acc[i][j], 0, 0, 0);
            __builtin_amdgcn_s_setprio(0);
        }
        __syncthreads();
        cur ^= 1;
    }

    #pragma unroll
    for (int i = 0; i < 8; ++i) {
        #pragma unroll
        for (int j = 0; j < 4; ++j) {
            const int row0 = m0 + wr + i * 16 + l4 * 4;
            const int col  = n0 + wc + j * 16 + l15;
            #pragma unroll
            for (int e = 0; e < 4; ++e)
                C[(long)(row0 + e) * 1024 + col] = f2bf(acc[i][j][e]);
        }
    }
}

// ---------------- partial S: Sp[kq][b,h] = W2[b][h-rows, kq-slice] @ wv^T ----------------

__global__ __launch_bounds__(256)
void k_attn_s(const ushort_t* __restrict__ W2, const ushort_t* __restrict__ wv,
              float* __restrict__ Sp)
{
    const int id = blockIdx.x;
    const int b = id & 7, h = (id >> 3) & 15, kq = id >> 7;
    const int tid = threadIdx.x;
    const int w = tid >> 6, lane = tid & 63;
    const int l15 = lane & 15, l4 = lane >> 4;

    f32x4 sf[4] = {};
    const int k0 = kq * 256;
    const ushort_t* pa  = W2 + (long)b * 1048576 + (long)(h * 64 + w * 16 + l15) * 1024 + k0 + l4 * 8;
    const ushort_t* pb0 = wv + (long)(h * 64 + l15) * 1024 + k0 + l4 * 8;

    #pragma unroll
    for (int kt = 0; kt < 256; kt += 32) {
        bf16x8 a = *(const bf16x8*)(pa + kt);
        #pragma unroll
        for (int nf = 0; nf < 4; ++nf) {
            bf16x8 bb = *(const bf16x8*)(pb0 + (long)(nf * 16) * 1024 + kt);
            sf[nf] = __builtin_amdgcn_mfma_f32_16x16x32_bf16(a, bb, sf[nf], 0, 0, 0);
        }
    }

    float* outp = Sp + ((long)kq * 128 + b * 16 + h) * 4096;
    #pragma unroll
    for (int nf = 0; nf < 4; ++nf)
        #pragma unroll
        for (int j = 0; j < 4; ++j)
            outp[(w * 16 + l4 * 4 + j) * 64 + nf * 16 + l15] = sf[nf][j];
}

// ---------------- softmax: su + sum 4 partials + rank-1 bias + causal softmax -> PT ----------------

__global__ __launch_bounds__(256)
void k_soft(const float* __restrict__ Sp, const ushort_t* __restrict__ wu,
            const float* __restrict__ xsum, const float* __restrict__ wvb,
            ushort_t* __restrict__ PT)
{
    __shared__ ushort_t PA[64 * 72];
    __shared__ float su_s[64];
    const int b = blockIdx.x & 7, h = blockIdx.x >> 3;
    const int tid = threadIdx.x;
    const int w = tid >> 6, lane = tid & 63;
    const int l15 = lane & 15, l4 = lane >> 4;

    {
        const int rr = tid >> 2, q4 = tid & 3;
        const ushort_t* pw = wu + (long)(h * 64 + rr) * 1024 + q4 * 256;
        const float* px = xsum + b * 1024 + q4 * 256;
        float s = 0.0f;
        #pragma unroll
        for (int i = 0; i < 32; ++i) {
            bf16x8 a = *(const bf16x8*)(pw + i * 8);
            float4 f0 = *(const float4*)(px + i * 8);
            float4 f1 = *(const float4*)(px + i * 8 + 4);
            s += (float)a[0] * f0.x + (float)a[1] * f0.y + (float)a[2] * f0.z + (float)a[3] * f0.w
               + (float)a[4] * f1.x + (float)a[5] * f1.y + (float)a[6] * f1.z + (float)a[7] * f1.w;
        }
        s += __shfl_xor(s, 1, 64);
        s += __shfl_xor(s, 2, 64);
        if (q4 == 0) su_s[rr] = s;
    }

    const float* s0 = Sp + ((long)b * 16 + h) * 4096;
    const float scale = 0.03125f;
    const int rb = w * 16 + l4 * 4;
    #pragma unroll
    for (int j = 0; j < 4; ++j) {
        const int srowi = rb + j;
        const float suv = su_s[srowi];
        float v[4];
        #pragma unroll
        for (int nf = 0; nf < 4; ++nf) {
            const int col = nf * 16 + l15;
            const int idx = srowi * 64 + col;
            const float sv = s0[idx] + s0[idx + 524288] + s0[idx + 1048576] + s0[idx + 1572864]
                           + suv * wvb[h * 64 + col];
            v[nf] = (col <= srowi) ? sv * scale : -3.0e38f;
        }
        float mx = fmaxf(fmaxf(v[0], v[1]), fmaxf(v[2], v[3]));
        #pragma unroll
        for (int o = 1; o < 16; o <<= 1) mx = fmaxf(mx, __shfl_xor(mx, o, 64));
        float s = 0.0f;
        #pragma unroll
        for (int nf = 0; nf < 4; ++nf) { v[nf] = __expf(v[nf] - mx); s += v[nf]; }
        #pragma unroll
        for (int o = 1; o < 16; o <<= 1) s += __shfl_xor(s, o, 64);
        const float inv = 1.0f / s;
        #pragma unroll
        for (int nf = 0; nf < 4; ++nf)
            PA[srowi * 72 + nf * 16 + l15] = f2bf(v[nf] * inv);
    }
    __syncthreads();

    const int d = tid >> 2, qq = tid & 3;
    unsigned wds[8];
    #pragma unroll
    for (int u2 = 0; u2 < 8; ++u2) {
        unsigned lo = PA[(qq * 16 + 2 * u2) * 72 + d];
        unsigned hi = PA[(qq * 16 + 2 * u2 + 1) * 72 + d];
        wds[u2] = lo | (hi << 16);
    }
    ushort_t* dst = PT + ((long)b * 64 + d) * 1024 + h * 64 + qq * 16;
    uint4 p0; unsigned* q0 = (unsigned*)&p0;
    q0[0] = wds[0]; q0[1] = wds[1]; q0[2] = wds[2]; q0[3] = wds[3];
    uint4 p1; unsigned* q1 = (unsigned*)&p1;
    q1[0] = wds[4]; q1[1] = wds[5]; q1[2] = wds[6]; q1[3] = wds[7];
    *(uint4*)dst = p0;
    *(uint4*)(dst + 8) = p1;
}

// ---------------- G-GEMM: GT = (x @ PT[b]^T)^T, 64x64 tile, K=1024, dbuf + B-reg-prefetch ----------------

__global__ __launch_bounds__(256)
void k_gg(const ushort_t* __restrict__ A, const ushort_t* __restrict__ Bt,
          ushort_t* __restrict__ C)
{
    __shared__ ushort_t smem[8448];
    const int id = blockIdx.x;
    const int tid = threadIdx.x;
    const int w = tid >> 6, lane = tid & 63;
    const int l15 = lane & 15, l4 = lane >> 4;

    const int b = id & 7, tl = id >> 3;
    const int m0 = (b * 32 + tl) * 64;
    const ushort_t* Ab = A + (long)m0 * 1024;
    const ushort_t* Bb = Bt + (long)b * 65536;

    const int wr = (w >> 1) * 32, wc = (w & 1) * 32;
    f32x4 acc[2][2] = {};
    const int srow = lane >> 3;
    const int gchunk = (lane & 7) ^ srow;

    #pragma unroll
    for (int q = 0; q < 2; ++q) {
        const int seg = w * 2 + q;
        async16(Ab + (long)(seg * 8 + srow) * 1024 + gchunk * 8, (char*)smem + seg * 1024);
    }
    bf16x8 bcur[2][2], bnxt[2][2];
    #pragma unroll
    for (int kk = 0; kk < 2; ++kk)
        #pragma unroll
        for (int nf = 0; nf < 2; ++nf)
            bcur[kk][nf] = *(const bf16x8*)&Bb[(long)(wc + nf * 16 + l15) * 1024 + kk * 32 + l4 * 8];
    __syncthreads();

    int cur = 0;
    for (int kt = 0; kt < 1024; kt += 64) {
        if (kt + 64 < 1024) {
            const int nb = cur ^ 1;
            #pragma unroll
            for (int q = 0; q < 2; ++q) {
                const int seg = w * 2 + q;
                async16(Ab + (long)(seg * 8 + srow) * 1024 + kt + 64 + gchunk * 8,
                        (char*)smem + nb * 8448 + seg * 1024);
            }
            #pragma unroll
            for (int kk = 0; kk < 2; ++kk)
                #pragma unroll
                for (int nf = 0; nf < 2; ++nf)
                    bnxt[kk][nf] = *(const bf16x8*)&Bb[(long)(wc + nf * 16 + l15) * 1024 + kt + 64 + kk * 32 + l4 * 8];
        }
        const ushort_t* Acur = smem + cur * 4224;
        #pragma unroll
        for (int kk = 0; kk < 2; ++kk) {
            const int swz = ((kk * 4 + l4) ^ (l15 & 7)) * 8;
            bf16x8 af[2];
            #pragma unroll
            for (int i = 0; i < 2; ++i)
                af[i] = *(const bf16x8*)&Acur[(wr + i * 16 + l15) * 64 + swz];
            __builtin_amdgcn_s_setprio(1);
            #pragma unroll
            for (int i = 0; i < 2; ++i)
                #pragma unroll
                for (int nf = 0; nf < 2; ++nf)
                    acc[i][nf] = __builtin_amdgcn_mfma_f32_16x16x32_bf16(af[i], bcur[kk][nf], acc[i][nf], 0, 0, 0);
            __builtin_amdgcn_s_setprio(0);
        }
        __syncthreads();
        #pragma unroll
        for (int kk = 0; kk < 2; ++kk)
            #pragma unroll
            for (int nf = 0; nf < 2; ++nf)
                bcur[kk][nf] = bnxt[kk][nf];
        cur ^= 1;
    }

    #pragma unroll
    for (int i = 0; i < 2; ++i)
        #pragma unroll
        for (int nf = 0; nf < 2; ++nf)
            #pragma unroll
            for (int e = 0; e < 4; ++e)
                smem[(wr + i * 16 + l4 * 4 + e) * 66 + wc + nf * 16 + l15] = f2bf(acc[i][nf][e]);
    __syncthreads();
    const int d = tid >> 2, qq = tid & 3;
    unsigned wds[8];
    #pragma unroll
    for (int u = 0; u < 8; ++u) {
        const int m = qq * 16 + u * 2;
        unsigned lo = smem[m * 66 + d];
        unsigned hi = smem[(m + 1) * 66 + d];
        wds[u] = lo | (hi << 16);
    }
    uint4 p0; unsigned* q0 = (unsigned*)&p0;
    q0[0] = wds[0]; q0[1] = wds[1]; q0[2] = wds[2]; q0[3] = wds[3];
    uint4 p1; unsigned* q1 = (unsigned*)&p1;
    q1[0] = wds[4]; q1[1] = wds[5]; q1[2] = wds[6]; q1[3] = wds[7];
    *(uint4*)&C[(long)d * 16384 + m0 + qq * 16] = p0;
    *(uint4*)&C[(long)d * 16384 + m0 + qq * 16 + 8] = p1;
}

// ---------------- fused Q + out: per (z, o-tile 64) ----------------
// Phase A: Qp = cproj[o-rows] @ Gp[z] (K=1024, B-reg-prefetch) -> LDS bf16
// Phase B: out = helperT @ Qp^T + cpb; LDS-staged 256-B contiguous fp32 writes

__global__ __launch_bounds__(256)
void k_qout(const ushort_t* __restrict__ cproj, const ushort_t* __restrict__ GT,
            const ushort_t* __restrict__ helperT, const float* __restrict__ cpb,
            float* __restrict__ out)
{
    __shared__ ushort_t smem[8448];
    __shared__ ushort_t Qp[64 * 72];
    __shared__ float Lw[4][64 * 68];     // per-wave 64x64 f32 stage (pitch 68 for 16B-aligned rows)
    const int id = blockIdx.x;
    const int z = id & 15, ot = id >> 4;
    const int o0 = ot * 64;
    const int tid = threadIdx.x;
    const int w = tid >> 6, lane = tid & 63;
    const int l15 = lane & 15, l4 = lane >> 4;

    const ushort_t* Ab = cproj + (long)o0 * 1024;
    const ushort_t* Bb = GT + (long)z * 1024;

    const int wr = (w >> 1) * 32, wc = (w & 1) * 32;
    f32x4 acc[2][2] = {};
    const int srow = lane >> 3;
    const int gchunk = (lane & 7) ^ srow;

    #pragma unroll
    for (int q = 0; q < 2; ++q) {
        const int seg = w * 2 + q;
        async16(Ab + (long)(seg * 8 + srow) * 1024 + gchunk * 8, (char*)smem + seg * 1024);
    }
    bf16x8 bcur[2][2], bnxt[2][2];
    #pragma unroll
    for (int kk = 0; kk < 2; ++kk)
        #pragma unroll
        for (int nf = 0; nf < 2; ++nf)
            bcur[kk][nf] = *(const bf16x8*)&Bb[(long)(wc + nf * 16 + l15) * 16384 + kk * 32 + l4 * 8];
    __syncthreads();

    int cur = 0;
    for (int kt = 0; kt < 1024; kt += 64) {
        if (kt + 64 < 1024) {
            const int nb = cur ^ 1;
            #pragma unroll
            for (int q = 0; q < 2; ++q) {
                const int seg = w * 2 + q;
                async16(Ab + (long)(seg * 8 + srow) * 1024 + kt + 64 + gchunk * 8,
                        (char*)smem + nb * 8448 + seg * 1024);
            }
            #pragma unroll
            for (int kk = 0; kk < 2; ++kk)
                #pragma unroll
                for (int nf = 0; nf < 2; ++nf)
                    bnxt[kk][nf] = *(const bf16x8*)&Bb[(long)(wc + nf * 16 + l15) * 16384 + kt + 64 + kk * 32 + l4 * 8];
        }
        const ushort_t* Acur = smem + cur * 4224;
        #pragma unroll
        for (int kk = 0; kk < 2; ++kk) {
            const int swz = ((kk * 4 + l4) ^ (l15 & 7)) * 8;
            bf16x8 af[2];
            #pragma unroll
            for (int i = 0; i < 2; ++i)
                af[i] = *(const bf16x8*)&Acur[(wr + i * 16 + l15) * 64 + swz];
            __builtin_amdgcn_s_setprio(1);
            #pragma unroll
            for (int i = 0; i < 2; ++i)
                #pragma unroll
                for (int nf = 0; nf < 2; ++nf)
                    acc[i][nf] = __builtin_amdgcn_mfma_f32_16x16x32_bf16(af[i], bcur[kk][nf], acc[i][nf], 0, 0, 0);
            __builtin_amdgcn_s_setprio(0);
        }
        __syncthreads();
        #pragma unroll
        for (int kk = 0; kk < 2; ++kk)
            #pragma unroll
            for (int nf = 0; nf < 2; ++nf)
                bcur[kk][nf] = bnxt[kk][nf];
        cur ^= 1;
    }

    #pragma unroll
    for (int i = 0; i < 2; ++i)
        #pragma unroll
        for (int nf = 0; nf < 2; ++nf)
            #pragma unroll
            for (int e = 0; e < 4; ++e)
                Qp[(wr + i * 16 + l4 * 4 + e) * 72 + wc + nf * 16 + l15] = f2bf(acc[i][nf][e]);
    __syncthreads();

    float cb[4];
    #pragma unroll
    for (int nf = 0; nf < 4; ++nf) cb[nf] = cpb[o0 + nf * 16 + l15];
    float* O = out + (long)(z >> 1) * 2097152 + (long)(z & 1) * 1024;

    bf16x8 bfr[4][2];
    #pragma unroll
    for (int kk = 0; kk < 2; ++kk)
        #pragma unroll
        for (int nf = 0; nf < 4; ++nf)
            bfr[nf][kk] = *(const bf16x8*)&Qp[(nf * 16 + l15) * 72 + kk * 32 + l4 * 8];

    float* LW = &Lw[w][0];
    for (int mc = 0; mc < 4; ++mc) {
        const int mt = w * 4 + mc;
        f32x4 a2[4][4] = {};
        #pragma unroll
        for (int kk = 0; kk < 2; ++kk) {
            bf16x8 af[4];
            #pragma unroll
            for (int i = 0; i < 4; ++i)
                af[i] = *(const bf16x8*)&helperT[(long)(mt * 64 + i * 16 + l15) * 64 + kk * 32 + l4 * 8];
            #pragma unroll
            for (int i = 0; i < 4; ++i)
                #pragma unroll
                for (int nf = 0; nf < 4; ++nf)
                    a2[i][nf] = __builtin_amdgcn_mfma_f32_16x16x32_bf16(af[i], bfr[nf][kk], a2[i][nf], 0, 0, 0);
        }
        // stage (with bias) to per-wave LDS, then write 256-B-contiguous fp32 rows
        #pragma unroll
        for (int i = 0; i < 4; ++i)
            #pragma unroll
            for (int nf = 0; nf < 4; ++nf)
                #pragma unroll
                for (int e = 0; e < 4; ++e)
                    LW[(i * 16 + l4 * 4 + e) * 68 + nf * 16 + l15] = a2[i][nf][e] + cb[nf];
        #pragma unroll
        for (int rr = 0; rr < 16; ++rr) {
            const int row = rr * 4 + l4;                 // c-local 0..63 (4 rows per instr)
            const int c = mt * 64 + row;
            float4 v = *(const float4*)&LW[row * 68 + l15 * 4];
            *(float4*)&O[(long)c * 2048 + o0 + l15 * 4] = v;
        }
    }
}

// ---------------- launch ----------------

extern "C" void kernel_launch(void* const* d_in, const int* in_sizes, int n_in,
                              void* d_out, int out_size, void* d_ws, size_t ws_size,
                              hipStream_t stream)
{
    (void)in_sizes; (void)n_in; (void)out_size; (void)ws_size;
    const float* x   = (const float*)d_in[0];
    const float* wu  = (const float*)d_in[1];
    const float* wv  = (const float*)d_in[2];
    const float* wvb = (const float*)d_in[3];
    const float* hw  = (const float*)d_in[4];
    const float* cpw = (const float*)d_in[5];
    const float* cpb = (const float*)d_in[6];
    float* out = (float*)d_out;

    char* ws = (char*)d_ws;
    ushort_t* x_bf    = (ushort_t*)(ws);                   // 32 MB  [16384][1024]
    ushort_t* xT_bf   = (ushort_t*)(ws + 33554432L);       // 32 MB  [8][1024][2048]
    ushort_t* XtX     = (ushort_t*)(ws + 67108864L);       // 16 MB  [8][1024][1024]
    float*    Sp      = (float*)   (ws + 67108864L);       // 8 MB   (overlays XtX, dead after k_w2)
    ushort_t* W2      = (ushort_t*)(ws + 83886080L);       // 16 MB  [8][1024][1024]
    ushort_t* wu_bf   = (ushort_t*)(ws + 100663296L);      // 2 MB
    ushort_t* wv_bf   = (ushort_t*)(ws + 102760448L);      // 2 MB
    ushort_t* cproj   = (ushort_t*)(ws + 104857600L);      // 2 MB
    ushort_t* helperT = (ushort_t*)(ws + 106954752L);      // 128 KB [1024][64]
    ushort_t* PT      = (ushort_t*)(ws + 107085824L);      // 1 MB   [8][64][1024]
    ushort_t* GT      = (ushort_t*)(ws + 108134400L);      // 2 MB   [64][16384]
    float*    xsum    = (float*)   (ws + 112328704L);      // 32 KB  [8][1024]

    // P0: merged prep
    k_prep<<<2048, 256, 0, stream>>>(wu, wv, cpw, hw, wu_bf, wv_bf, cproj, helperT, xsum);

    // P1: x -> x_bf + xT_bf + xsum
    {
        dim3 g(8, 8, 8);
        k_trans<<<g, 256, 0, stream>>>(x, x_bf, xT_bf, xsum);
    }

    // XtX[b] = xT[b] @ xT[b]^T
    k_syrk<<<576, 256, 0, stream>>>(xT_bf, XtX);

    // W2[b] = wu @ XtX[b]
    k_w2<<<256, 256, 0, stream>>>(wu_bf, XtX, W2);

    // partial S (512 blocks)
    k_attn_s<<<512, 256, 0, stream>>>(W2, wv_bf, Sp);

    // su + combine + softmax -> PT
    k_soft<<<128, 256, 0, stream>>>(Sp, wu_bf, xsum, wvb, PT);

    // G = x @ PstackT -> GT
    k_gg<<<256, 256, 0, stream>>>(x_bf, PT, GT);

    // fused Q + out
    k_qout<<<256, 256, 0, stream>>>(cproj, GT, helperT, cpb, out);
}

// Round 12
// 144.786 us; speedup vs baseline: 1.1181x; 1.1181x over previous
//
#include <hip/hip_runtime.h>

typedef unsigned short ushort_t;
typedef __bf16 bf16x8 __attribute__((ext_vector_type(8)));
typedef float f32x4 __attribute__((ext_vector_type(4)));

__device__ __forceinline__ ushort_t f2bf(float f) {
    unsigned u = __builtin_bit_cast(unsigned, f);
    unsigned r = (u + 0x7fffu + ((u >> 16) & 1u)) >> 16;
    return (ushort_t)r;
}
__device__ __forceinline__ float bf2f(ushort_t u) {
    return __builtin_bit_cast(float, (unsigned)u << 16);
}

__device__ __forceinline__ void async16(const ushort_t* g, void* lds) {
    __builtin_amdgcn_global_load_lds(
        (const __attribute__((address_space(1))) void*)g,
        (__attribute__((address_space(3))) void*)lds, 16, 0, 0);
}

// ---------------- transpose + convert: x fp32 -> x_bf, xT_bf, xsum partials ----------------
// tile [256 t][128 c], grid (8,8,8). Per-block column sums stored (no atomics, no zeroing).

__global__ __launch_bounds__(256)
void k_trans(const float* __restrict__ x, ushort_t* __restrict__ xbf,
             ushort_t* __restrict__ xT, float* __restrict__ xsum_p)
{
    __shared__ ushort_t T[256 * 130];
    __shared__ float xs[128];
    const int t0 = blockIdx.x * 256, c0 = blockIdx.y * 128, b = blockIdx.z;
    const int tid = threadIdx.x;
    const int w = tid >> 6, lane = tid & 63;
    const int lh = lane >> 5;
    const int k32 = lane & 31;

    if (tid < 128) xs[tid] = 0.0f;
    __syncthreads();

    float ps[4] = {0.f, 0.f, 0.f, 0.f};
    #pragma unroll 4
    for (int it = 0; it < 32; ++it) {
        const int r = it * 8 + w * 2 + lh;
        const long gi = ((long)(b * 2048 + t0 + r)) * 1024 + c0 + k32 * 4;
        float4 f = *(const float4*)&x[gi];
        ushort4 o;
        o.x = f2bf(f.x); o.y = f2bf(f.y); o.z = f2bf(f.z); o.w = f2bf(f.w);
        *(ushort4*)&xbf[gi] = o;
        *(ushort4*)&T[r * 130 + k32 * 4] = o;
        ps[0] += bf2f(o.x); ps[1] += bf2f(o.y); ps[2] += bf2f(o.z); ps[3] += bf2f(o.w);
    }
    #pragma unroll
    for (int k = 0; k < 4; ++k) ps[k] += __shfl_xor(ps[k], 32, 64);
    if (lh == 0) {
        #pragma unroll
        for (int k = 0; k < 4; ++k) atomicAdd(&xs[k32 * 4 + k], ps[k]);
    }
    __syncthreads();

    for (int i = 0; i < 32; ++i) {
        const int c = w * 32 + i;
        ushort_t* dst = &xT[((long)(b * 1024 + c0 + c)) * 2048 + t0];
        #pragma unroll
        for (int j = 0; j < 2; ++j) {
            const int t = 2 * lane + 128 * j;
            unsigned lo = T[t * 130 + c];
            unsigned hi = T[(t + 1) * 130 + c];
            *(unsigned*)(dst + 128 * j + 2 * lane) = lo | (hi << 16);
        }
    }
    if (tid < 128)
        xsum_p[(long)blockIdx.x * 8192 + b * 1024 + c0 + tid] = xs[tid];
}

// ---------------- SYRK (+ folded weight prep): XtX[b] = xT[b] @ xT[b]^T ----------------

__global__ __launch_bounds__(256)
void k_syrk(const ushort_t* __restrict__ xT, ushort_t* __restrict__ XtX,
            const float* __restrict__ wu, const float* __restrict__ wv,
            const float* __restrict__ cpw, const float* __restrict__ hw,
            ushort_t* __restrict__ wu_bf, ushort_t* __restrict__ wv_bf,
            ushort_t* __restrict__ cproj, ushort_t* __restrict__ hT)
{
    __shared__ ushort_t smem[24576];
    // folded weight prep (grid-stride; consumers all launch after syrk)
    {
        int i = blockIdx.x * 256 + threadIdx.x;
        const int st = gridDim.x * 256;
        for (; i < 1048576; i += st) {
            wu_bf[i] = f2bf(wu[i]);
            wv_bf[i] = f2bf(wv[i]);
            cproj[i] = f2bf(cpw[i]);
            if (i < 65536) {
                int cc = i >> 6, d = i & 63;
                hT[i] = f2bf(hw[d * 1024 + cc]);   // helperT[c][d] = helper_w[d][c]
            }
        }
    }

    const int id = blockIdx.x;
    const int z = id & 7;
    int L = id >> 3, bi = 0;
    while (L >= 16 - 2 * bi) { L -= 16 - 2 * bi; ++bi; }
    const int cj = 2 * bi + L;
    const ushort_t* base = xT + (long)z * 2097152;
    const ushort_t* Ab = base + (long)bi * 128 * 2048;
    const ushort_t* Bb = base + (long)cj * 64 * 2048;
    ushort_t* C = XtX + (long)z * 1048576;
    const int tid = threadIdx.x;
    const int w = tid >> 6;
    const int lane = tid & 63;
    const int l15 = lane & 15, l4 = lane >> 4;
    const int wr = (w >> 1) * 64, wc = (w & 1) * 32;

    f32x4 acc[4][2] = {};
    const int srow = lane >> 3;
    const int gchunk = (lane & 7) ^ srow;

    #pragma unroll
    for (int q = 0; q < 4; ++q) {
        const int seg = w * 4 + q;
        async16(Ab + (long)(seg * 8 + srow) * 2048 + gchunk * 8, (char*)smem + seg * 1024);
    }
    #pragma unroll
    for (int q = 0; q < 2; ++q) {
        const int seg = w * 2 + q;
        async16(Bb + (long)(seg * 8 + srow) * 2048 + gchunk * 8, (char*)smem + 32768 + seg * 1024);
    }
    __syncthreads();

    int cur = 0;
    for (int kt = 0; kt < 2048; kt += 64) {
        if (kt + 64 < 2048) {
            const int nb = cur ^ 1;
            #pragma unroll
            for (int q = 0; q < 4; ++q) {
                const int seg = w * 4 + q;
                async16(Ab + (long)(seg * 8 + srow) * 2048 + kt + 64 + gchunk * 8,
                        (char*)smem + nb * 16384 + seg * 1024);
            }
            #pragma unroll
            for (int q = 0; q < 2; ++q) {
                const int seg = w * 2 + q;
                async16(Bb + (long)(seg * 8 + srow) * 2048 + kt + 64 + gchunk * 8,
                        (char*)smem + 32768 + nb * 8192 + seg * 1024);
            }
        }
        const ushort_t* Acur = smem + cur * 8192;
        const ushort_t* Bcur = smem + 16384 + cur * 4096;
        #pragma unroll
        for (int kk = 0; kk < 2; ++kk) {
            bf16x8 af[4], bfr[2];
            const int swz = ((kk * 4 + l4) ^ (l15 & 7)) * 8;
            #pragma unroll
            for (int i = 0; i < 4; ++i)
                af[i] = *(const bf16x8*)&Acur[(wr + i * 16 + l15) * 64 + swz];
            #pragma unroll
            for (int nf = 0; nf < 2; ++nf)
                bfr[nf] = *(const bf16x8*)&Bcur[(wc + nf * 16 + l15) * 64 + swz];
            __builtin_amdgcn_s_setprio(1);
            #pragma unroll
            for (int i = 0; i < 4; ++i)
                #pragma unroll
                for (int nf = 0; nf < 2; ++nf)
                    acc[i][nf] = __builtin_amdgcn_mfma_f32_16x16x32_bf16(af[i], bfr[nf], acc[i][nf], 0, 0, 0);
            __builtin_amdgcn_s_setprio(0);
        }
        __syncthreads();
        cur ^= 1;
    }

    #pragma unroll
    for (int i = 0; i < 4; ++i) {
        #pragma unroll
        for (int nf = 0; nf < 2; ++nf) {
            const int row0 = bi * 128 + wr + i * 16 + l4 * 4;
            const int col  = cj * 64 + wc + nf * 16 + l15;
            #pragma unroll
            for (int e = 0; e < 4; ++e)
                C[(long)(row0 + e) * 1024 + col] = f2bf(acc[i][nf][e]);
        }
    }
    __syncthreads();
    #pragma unroll
    for (int i = 0; i < 4; ++i)
        #pragma unroll
        for (int nf = 0; nf < 2; ++nf)
            #pragma unroll
            for (int e = 0; e < 4; ++e)
                smem[(wr + i * 16 + l4 * 4 + e) * 66 + wc + nf * 16 + l15] = f2bf(acc[i][nf][e]);
    __syncthreads();
    const int nr = tid & 63;
    const int mh = tid >> 6;
    unsigned wds[16];
    #pragma unroll
    for (int u = 0; u < 16; ++u) {
        const int m = mh * 32 + u * 2;
        unsigned lo = smem[m * 66 + nr];
        unsigned hi = smem[(m + 1) * 66 + nr];
        wds[u] = lo | (hi << 16);
    }
    #pragma unroll
    for (int v = 0; v < 4; ++v) {
        uint4 pk; unsigned* pw = (unsigned*)&pk;
        pw[0] = wds[v * 4]; pw[1] = wds[v * 4 + 1]; pw[2] = wds[v * 4 + 2]; pw[3] = wds[v * 4 + 3];
        *(uint4*)&C[(long)(cj * 64 + nr) * 1024 + bi * 128 + mh * 32 + v * 8] = pk;
    }
}

// ---------------- W2 = wu @ XtX[b] : 256x128 tile, BK=64, dbuf, 96 KB LDS ----------------

__global__ __launch_bounds__(256)
void k_w2(const ushort_t* __restrict__ wu, const ushort_t* __restrict__ XtX,
          ushort_t* __restrict__ W2)
{
    __shared__ ushort_t smem[49152];
    const int id = blockIdx.x;
    const int z = id & 7;
    const int t = id >> 3;
    const int bx = t & 3, by = t >> 2;
    const int m0 = bx * 256, n0 = by * 128;
    const ushort_t* Ab = wu + (long)m0 * 1024;
    const ushort_t* Bb = XtX + (long)z * 1048576 + (long)n0 * 1024;
    ushort_t* C = W2 + (long)z * 1048576;
    const int tid = threadIdx.x;
    const int w = tid >> 6;
    const int lane = tid & 63;
    const int l15 = lane & 15, l4 = lane >> 4;
    const int wr = (w >> 1) * 128, wc = (w & 1) * 64;

    f32x4 acc[8][4] = {};
    const int srow = lane >> 3;
    const int gchunk = (lane & 7) ^ srow;

    #pragma unroll
    for (int q = 0; q < 8; ++q) {
        const int seg = w * 8 + q;
        async16(Ab + (long)(seg * 8 + srow) * 1024 + gchunk * 8, (char*)smem + seg * 1024);
    }
    #pragma unroll
    for (int q = 0; q < 4; ++q) {
        const int seg = w * 4 + q;
        async16(Bb + (long)(seg * 8 + srow) * 1024 + gchunk * 8, (char*)smem + 65536 + seg * 1024);
    }
    __syncthreads();

    int cur = 0;
    for (int kt = 0; kt < 1024; kt += 64) {
        if (kt + 64 < 1024) {
            const int nb = cur ^ 1;
            #pragma unroll
            for (int q = 0; q < 8; ++q) {
                const int seg = w * 8 + q;
                async16(Ab + (long)(seg * 8 + srow) * 1024 + kt + 64 + gchunk * 8,
                        (char*)smem + nb * 32768 + seg * 1024);
            }
            #pragma unroll
            for (int q = 0; q < 4; ++q) {
                const int seg = w * 4 + q;
                async16(Bb + (long)(seg * 8 + srow) * 1024 + kt + 64 + gchunk * 8,
                        (char*)smem + 65536 + nb * 16384 + seg * 1024);
            }
        }
        const ushort_t* Acur = smem + cur * 16384;
        const ushort_t* Bcur = smem + 32768 + cur * 8192;
        #pragma unroll
        for (int kk = 0; kk < 2; ++kk) {
            bf16x8 af[8], bfr[4];
            const int swz = ((kk * 4 + l4) ^ (l15 & 7)) * 8;
            #pragma unroll
            for (int i = 0; i < 8; ++i)
                af[i] = *(const bf16x8*)&Acur[(wr + i * 16 + l15) * 64 + swz];
            #pragma unroll
            for (int j = 0; j < 4; ++j)
                bfr[j] = *(const bf16x8*)&Bcur[(wc + j * 16 + l15) * 64 + swz];
            __builtin_amdgcn_s_setprio(1);
            #pragma unroll
            for (int i = 0; i < 8; ++i)
                #pragma unroll
                for (int j = 0; j < 4; ++j)
                    acc[i][j] = __builtin_amdgcn_mfma_f32_16x16x32_bf16(af[i], bfr[j], acc[i][j], 0, 0, 0);
            __builtin_amdgcn_s_setprio(0);
        }
        __syncthreads();
        cur ^= 1;
    }

    #pragma unroll
    for (int i = 0; i < 8; ++i) {
        #pragma unroll
        for (int j = 0; j < 4; ++j) {
            const int row0 = m0 + wr + i * 16 + l4 * 4;
            const int col  = n0 + wc + j * 16 + l15;
            #pragma unroll
            for (int e = 0; e < 4; ++e)
                C[(long)(row0 + e) * 1024 + col] = f2bf(acc[i][j][e]);
        }
    }
}

// ---------------- partial S: Sp[kq][b,h] = W2[b][h-rows, kq-slice] @ wv^T ----------------

__global__ __launch_bounds__(256)
void k_attn_s(const ushort_t* __restrict__ W2, const ushort_t* __restrict__ wv,
              float* __restrict__ Sp)
{
    const int id = blockIdx.x;
    const int b = id & 7, h = (id >> 3) & 15, kq = id >> 7;
    const int tid = threadIdx.x;
    const int w = tid >> 6, lane = tid & 63;
    const int l15 = lane & 15, l4 = lane >> 4;

    f32x4 sf[4] = {};
    const int k0 = kq * 256;
    const ushort_t* pa  = W2 + (long)b * 1048576 + (long)(h * 64 + w * 16 + l15) * 1024 + k0 + l4 * 8;
    const ushort_t* pb0 = wv + (long)(h * 64 + l15) * 1024 + k0 + l4 * 8;

    #pragma unroll
    for (int kt = 0; kt < 256; kt += 32) {
        bf16x8 a = *(const bf16x8*)(pa + kt);
        #pragma unroll
        for (int nf = 0; nf < 4; ++nf) {
            bf16x8 bb = *(const bf16x8*)(pb0 + (long)(nf * 16) * 1024 + kt);
            sf[nf] = __builtin_amdgcn_mfma_f32_16x16x32_bf16(a, bb, sf[nf], 0, 0, 0);
        }
    }

    float* outp = Sp + ((long)kq * 128 + b * 16 + h) * 4096;
    #pragma unroll
    for (int nf = 0; nf < 4; ++nf)
        #pragma unroll
        for (int j = 0; j < 4; ++j)
            outp[(w * 16 + l4 * 4 + j) * 64 + nf * 16 + l15] = sf[nf][j];
}

// ---------------- softmax: xsum-reduce + su + sum 4 partials + rank-1 bias + softmax -> PT ----------------

__global__ __launch_bounds__(256)
void k_soft(const float* __restrict__ Sp, const ushort_t* __restrict__ wu,
            const float* __restrict__ xsum_p, const float* __restrict__ wvb,
            ushort_t* __restrict__ PT)
{
    __shared__ ushort_t PA[64 * 72];
    __shared__ float su_s[64];
    __shared__ float xsv[1024];
    const int b = blockIdx.x & 7, h = blockIdx.x >> 3;
    const int tid = threadIdx.x;
    const int w = tid >> 6, lane = tid & 63;
    const int l15 = lane & 15, l4 = lane >> 4;

    // reduce the 8 xsum partials for batch b into LDS
    {
        const float* xp = xsum_p + (long)b * 1024;
        #pragma unroll
        for (int c = tid; c < 1024; c += 256) {
            float s = 0.0f;
            #pragma unroll
            for (int j = 0; j < 8; ++j) s += xp[(long)j * 8192 + c];
            xsv[c] = s;
        }
    }
    __syncthreads();

    // su for this block's 64 rows: 4 threads per row, same wave band
    {
        const int rr = tid >> 2, q4 = tid & 3;
        const ushort_t* pw = wu + (long)(h * 64 + rr) * 1024 + q4 * 256;
        const float* px = &xsv[q4 * 256];
        float s = 0.0f;
        #pragma unroll
        for (int i = 0; i < 32; ++i) {
            bf16x8 a = *(const bf16x8*)(pw + i * 8);
            float4 f0 = *(const float4*)(px + i * 8);
            float4 f1 = *(const float4*)(px + i * 8 + 4);
            s += (float)a[0] * f0.x + (float)a[1] * f0.y + (float)a[2] * f0.z + (float)a[3] * f0.w
               + (float)a[4] * f1.x + (float)a[5] * f1.y + (float)a[6] * f1.z + (float)a[7] * f1.w;
        }
        s += __shfl_xor(s, 1, 64);
        s += __shfl_xor(s, 2, 64);
        if (q4 == 0) su_s[rr] = s;   // consumed by same wave below
    }

    const float* s0 = Sp + ((long)b * 16 + h) * 4096;
    const float scale = 0.03125f;   // 1/sqrt(1024)
    const int rb = w * 16 + l4 * 4;
    #pragma unroll
    for (int j = 0; j < 4; ++j) {
        const int srowi = rb + j;
        const float suv = su_s[srowi];
        float v[4];
        #pragma unroll
        for (int nf = 0; nf < 4; ++nf) {
            const int col = nf * 16 + l15;
            const int idx = srowi * 64 + col;
            const float sv = s0[idx] + s0[idx + 524288] + s0[idx + 1048576] + s0[idx + 1572864]
                           + suv * wvb[h * 64 + col];
            v[nf] = (col <= srowi) ? sv * scale : -3.0e38f;
        }
        float mx = fmaxf(fmaxf(v[0], v[1]), fmaxf(v[2], v[3]));
        #pragma unroll
        for (int o = 1; o < 16; o <<= 1) mx = fmaxf(mx, __shfl_xor(mx, o, 64));
        float s = 0.0f;
        #pragma unroll
        for (int nf = 0; nf < 4; ++nf) { v[nf] = __expf(v[nf] - mx); s += v[nf]; }
        #pragma unroll
        for (int o = 1; o < 16; o <<= 1) s += __shfl_xor(s, o, 64);
        const float inv = 1.0f / s;
        #pragma unroll
        for (int nf = 0; nf < 4; ++nf)
            PA[srowi * 72 + nf * 16 + l15] = f2bf(v[nf] * inv);
    }
    __syncthreads();

    const int d = tid >> 2, qq = tid & 3;
    unsigned wds[8];
    #pragma unroll
    for (int u2 = 0; u2 < 8; ++u2) {
        unsigned lo = PA[(qq * 16 + 2 * u2) * 72 + d];
        unsigned hi = PA[(qq * 16 + 2 * u2 + 1) * 72 + d];
        wds[u2] = lo | (hi << 16);
    }
    ushort_t* dst = PT + ((long)b * 64 + d) * 1024 + h * 64 + qq * 16;
    uint4 p0; unsigned* q0 = (unsigned*)&p0;
    q0[0] = wds[0]; q0[1] = wds[1]; q0[2] = wds[2]; q0[3] = wds[3];
    uint4 p1; unsigned* q1 = (unsigned*)&p1;
    q1[0] = wds[4]; q1[1] = wds[5]; q1[2] = wds[6]; q1[3] = wds[7];
    *(uint4*)dst = p0;
    *(uint4*)(dst + 8) = p1;
}

// ---------------- G-GEMM: GT = (x @ PT[b]^T)^T, 64x64 tile, K=1024, dbuf ----------------

__global__ __launch_bounds__(256)
void k_gg(const ushort_t* __restrict__ A, const ushort_t* __restrict__ Bt,
          ushort_t* __restrict__ C)
{
    __shared__ ushort_t smem[8448];
    const int id = blockIdx.x;
    const int tid = threadIdx.x;
    const int w = tid >> 6, lane = tid & 63;
    const int l15 = lane & 15, l4 = lane >> 4;

    const int b = id & 7, tl = id >> 3;
    const int m0 = (b * 32 + tl) * 64;
    const ushort_t* Ab = A + (long)m0 * 1024;
    const ushort_t* Bb = Bt + (long)b * 65536;

    const int wr = (w >> 1) * 32, wc = (w & 1) * 32;
    f32x4 acc[2][2] = {};
    const int srow = lane >> 3;
    const int gchunk = (lane & 7) ^ srow;

    #pragma unroll
    for (int q = 0; q < 2; ++q) {
        const int seg = w * 2 + q;
        async16(Ab + (long)(seg * 8 + srow) * 1024 + gchunk * 8, (char*)smem + seg * 1024);
    }
    __syncthreads();

    int cur = 0;
    for (int kt = 0; kt < 1024; kt += 64) {
        if (kt + 64 < 1024) {
            const int nb = cur ^ 1;
            #pragma unroll
            for (int q = 0; q < 2; ++q) {
                const int seg = w * 2 + q;
                async16(Ab + (long)(seg * 8 + srow) * 1024 + kt + 64 + gchunk * 8,
                        (char*)smem + nb * 8448 + seg * 1024);
            }
        }
        const ushort_t* Acur = smem + cur * 4224;
        #pragma unroll
        for (int kk = 0; kk < 2; ++kk) {
            const int swz = ((kk * 4 + l4) ^ (l15 & 7)) * 8;
            bf16x8 af[2], bfr[2];
            #pragma unroll
            for (int i = 0; i < 2; ++i)
                af[i] = *(const bf16x8*)&Acur[(wr + i * 16 + l15) * 64 + swz];
            #pragma unroll
            for (int nf = 0; nf < 2; ++nf)
                bfr[nf] = *(const bf16x8*)&Bb[(long)(wc + nf * 16 + l15) * 1024 + kt + kk * 32 + l4 * 8];
            __builtin_amdgcn_s_setprio(1);
            #pragma unroll
            for (int i = 0; i < 2; ++i)
                #pragma unroll
                for (int nf = 0; nf < 2; ++nf)
                    acc[i][nf] = __builtin_amdgcn_mfma_f32_16x16x32_bf16(af[i], bfr[nf], acc[i][nf], 0, 0, 0);
            __builtin_amdgcn_s_setprio(0);
        }
        __syncthreads();
        cur ^= 1;
    }

    #pragma unroll
    for (int i = 0; i < 2; ++i)
        #pragma unroll
        for (int nf = 0; nf < 2; ++nf)
            #pragma unroll
            for (int e = 0; e < 4; ++e)
                smem[(wr + i * 16 + l4 * 4 + e) * 66 + wc + nf * 16 + l15] = f2bf(acc[i][nf][e]);
    __syncthreads();
    const int d = tid >> 2, qq = tid & 3;
    unsigned wds[8];
    #pragma unroll
    for (int u = 0; u < 8; ++u) {
        const int m = qq * 16 + u * 2;
        unsigned lo = smem[m * 66 + d];
        unsigned hi = smem[(m + 1) * 66 + d];
        wds[u] = lo | (hi << 16);
    }
    uint4 p0; unsigned* q0 = (unsigned*)&p0;
    q0[0] = wds[0]; q0[1] = wds[1]; q0[2] = wds[2]; q0[3] = wds[3];
    uint4 p1; unsigned* q1 = (unsigned*)&p1;
    q1[0] = wds[4]; q1[1] = wds[5]; q1[2] = wds[6]; q1[3] = wds[7];
    *(uint4*)&C[(long)d * 16384 + m0 + qq * 16] = p0;
    *(uint4*)&C[(long)d * 16384 + m0 + qq * 16 + 8] = p1;
}

// ---------------- fused Q + out: per (z, o-tile 64) ----------------

__global__ __launch_bounds__(256)
void k_qout(const ushort_t* __restrict__ cproj, const ushort_t* __restrict__ GT,
            const ushort_t* __restrict__ helperT, const float* __restrict__ cpb,
            float* __restrict__ out)
{
    __shared__ ushort_t smem[8448];
    __shared__ ushort_t Qp[64 * 72];
    const int id = blockIdx.x;
    const int z = id & 15, ot = id >> 4;
    const int o0 = ot * 64;
    const int tid = threadIdx.x;
    const int w = tid >> 6, lane = tid & 63;
    const int l15 = lane & 15, l4 = lane >> 4;

    const ushort_t* Ab = cproj + (long)o0 * 1024;
    const ushort_t* Bb = GT + (long)z * 1024;

    const int wr = (w >> 1) * 32, wc = (w & 1) * 32;
    f32x4 acc[2][2] = {};
    const int srow = lane >> 3;
    const int gchunk = (lane & 7) ^ srow;

    #pragma unroll
    for (int q = 0; q < 2; ++q) {
        const int seg = w * 2 + q;
        async16(Ab + (long)(seg * 8 + srow) * 1024 + gchunk * 8, (char*)smem + seg * 1024);
    }
    __syncthreads();

    int cur = 0;
    for (int kt = 0; kt < 1024; kt += 64) {
        if (kt + 64 < 1024) {
            const int nb = cur ^ 1;
            #pragma unroll
            for (int q = 0; q < 2; ++q) {
                const int seg = w * 2 + q;
                async16(Ab + (long)(seg * 8 + srow) * 1024 + kt + 64 + gchunk * 8,
                        (char*)smem + nb * 8448 + seg * 1024);
            }
        }
        const ushort_t* Acur = smem + cur * 4224;
        #pragma unroll
        for (int kk = 0; kk < 2; ++kk) {
            const int swz = ((kk * 4 + l4) ^ (l15 & 7)) * 8;
            bf16x8 af[2], bfr[2];
            #pragma unroll
            for (int i = 0; i < 2; ++i)
                af[i] = *(const bf16x8*)&Acur[(wr + i * 16 + l15) * 64 + swz];
            #pragma unroll
            for (int nf = 0; nf < 2; ++nf)
                bfr[nf] = *(const bf16x8*)&Bb[(long)(wc + nf * 16 + l15) * 16384 + kt + kk * 32 + l4 * 8];
            __builtin_amdgcn_s_setprio(1);
            #pragma unroll
            for (int i = 0; i < 2; ++i)
                #pragma unroll
                for (int nf = 0; nf < 2; ++nf)
                    acc[i][nf] = __builtin_amdgcn_mfma_f32_16x16x32_bf16(af[i], bfr[nf], acc[i][nf], 0, 0, 0);
            __builtin_amdgcn_s_setprio(0);
        }
        __syncthreads();
        cur ^= 1;
    }

    #pragma unroll
    for (int i = 0; i < 2; ++i)
        #pragma unroll
        for (int nf = 0; nf < 2; ++nf)
            #pragma unroll
            for (int e = 0; e < 4; ++e)
                Qp[(wr + i * 16 + l4 * 4 + e) * 72 + wc + nf * 16 + l15] = f2bf(acc[i][nf][e]);
    __syncthreads();

    float cb[4];
    #pragma unroll
    for (int nf = 0; nf < 4; ++nf) cb[nf] = cpb[o0 + nf * 16 + l15];
    float* O = out + (long)(z >> 1) * 2097152 + (long)(z & 1) * 1024;

    bf16x8 bfr[4][2];
    #pragma unroll
    for (int kk = 0; kk < 2; ++kk)
        #pragma unroll
        for (int nf = 0; nf < 4; ++nf)
            bfr[nf][kk] = *(const bf16x8*)&Qp[(nf * 16 + l15) * 72 + kk * 32 + l4 * 8];

    for (int mc = 0; mc < 4; ++mc) {
        const int mt = w * 4 + mc;
        f32x4 a2[4][4] = {};
        #pragma unroll
        for (int kk = 0; kk < 2; ++kk) {
            bf16x8 af[4];
            #pragma unroll
            for (int i = 0; i < 4; ++i)
                af[i] = *(const bf16x8*)&helperT[(long)(mt * 64 + i * 16 + l15) * 64 + kk * 32 + l4 * 8];
            #pragma unroll
            for (int i = 0; i < 4; ++i)
                #pragma unroll
                for (int nf = 0; nf < 4; ++nf)
                    a2[i][nf] = __builtin_amdgcn_mfma_f32_16x16x32_bf16(af[i], bfr[nf][kk], a2[i][nf], 0, 0, 0);
        }
        #pragma unroll
        for (int i = 0; i < 4; ++i) {
            #pragma unroll
            for (int nf = 0; nf < 4; ++nf) {
                const int c = mt * 64 + i * 16 + l4 * 4;
                const int o = o0 + nf * 16 + l15;
                #pragma unroll
                for (int e = 0; e < 4; ++e)
                    O[(long)(c + e) * 2048 + o] = a2[i][nf][e] + cb[nf];
            }
        }
    }
}

// ---------------- launch ----------------

extern "C" void kernel_launch(void* const* d_in, const int* in_sizes, int n_in,
                              void* d_out, int out_size, void* d_ws, size_t ws_size,
                              hipStream_t stream)
{
    (void)in_sizes; (void)n_in; (void)out_size; (void)ws_size;
    const float* x   = (const float*)d_in[0];
    const float* wu  = (const float*)d_in[1];
    const float* wv  = (const float*)d_in[2];
    const float* wvb = (const float*)d_in[3];
    const float* hw  = (const float*)d_in[4];
    const float* cpw = (const float*)d_in[5];
    const float* cpb = (const float*)d_in[6];
    float* out = (float*)d_out;

    char* ws = (char*)d_ws;
    ushort_t* x_bf    = (ushort_t*)(ws);                   // 32 MB  [16384][1024]
    ushort_t* xT_bf   = (ushort_t*)(ws + 33554432L);       // 32 MB  [8][1024][2048]
    ushort_t* XtX     = (ushort_t*)(ws + 67108864L);       // 16 MB  [8][1024][1024]
    float*    Sp      = (float*)   (ws + 67108864L);       // 8 MB   (overlays XtX, dead after k_w2)
    ushort_t* W2      = (ushort_t*)(ws + 83886080L);       // 16 MB  [8][1024][1024]
    ushort_t* wu_bf   = (ushort_t*)(ws + 100663296L);      // 2 MB
    ushort_t* wv_bf   = (ushort_t*)(ws + 102760448L);      // 2 MB
    ushort_t* cproj   = (ushort_t*)(ws + 104857600L);      // 2 MB
    ushort_t* helperT = (ushort_t*)(ws + 106954752L);      // 128 KB [1024][64]
    ushort_t* PT      = (ushort_t*)(ws + 107085824L);      // 1 MB   [8][64][1024]
    ushort_t* GT      = (ushort_t*)(ws + 108134400L);      // 2 MB   [64][16384]
    float*    xsum_p  = (float*)   (ws + 112328704L);      // 256 KB [8 t0][8 b][1024 c]

    // P1: x -> x_bf + xT_bf + xsum partials
    {
        dim3 g(8, 8, 8);
        k_trans<<<g, 256, 0, stream>>>(x, x_bf, xT_bf, xsum_p);
    }

    // XtX[b] = xT[b] @ xT[b]^T  (+ folded weight conversions)
    k_syrk<<<576, 256, 0, stream>>>(xT_bf, XtX, wu, wv, cpw, hw,
                                    wu_bf, wv_bf, cproj, helperT);

    // W2[b] = wu @ XtX[b]
    k_w2<<<256, 256, 0, stream>>>(wu_bf, XtX, W2);

    // partial S (512 blocks)
    k_attn_s<<<512, 256, 0, stream>>>(W2, wv_bf, Sp);

    // xsum-reduce + su + combine + softmax -> PT
    k_soft<<<128, 256, 0, stream>>>(Sp, wu_bf, xsum_p, wvb, PT);

    // G = x @ PstackT -> GT
    k_gg<<<256, 256, 0, stream>>>(x_bf, PT, GT);

    // fused Q + out
    k_qout<<<256, 256, 0, stream>>>(cproj, GT, helperT, cpb, out);
}